// Round 2
// baseline (545.983 us; speedup 1.0000x reference)
//
#include <hip/hip_runtime.h>

#define N_ROWS 65536
#define DIM 64
#define KCB 1024
#define Q_ELEMS 4194304   // 64*64*32*32
#define RPB 64            // rows per block (1 row per lane)
#define NWAVES 4          // waves per block; each owns a K-quarter
#define KQ 256            // codewords per wave

// ws layout (bytes): [0,4096) float wn2[1024]; [4096,8192) float partial[1024]

// Bit-exact replica of numpy's pairwise sum of squares for 64 fp32 values.
__device__ __forceinline__ float np_pairwise_sumsq64(const float* v) {
#pragma clang fp contract(off)
    float r[8];
#pragma unroll
    for (int j = 0; j < 8; ++j) r[j] = v[j] * v[j];
#pragma unroll
    for (int i = 8; i < 64; i += 8) {
#pragma unroll
        for (int j = 0; j < 8; ++j) {
            float s = v[i + j] * v[i + j];
            r[j] = r[j] + s;
        }
    }
    return ((r[0] + r[1]) + (r[2] + r[3])) + ((r[4] + r[5]) + (r[6] + r[7]));
}

__global__ __launch_bounds__(64) void wnorm_kernel(const float* __restrict__ w,
                                                   float* __restrict__ wn2) {
    __shared__ float tile[64][65];
    const int t = threadIdx.x;
    const size_t base = (size_t)blockIdx.x * 64 * DIM;
#pragma unroll 4
    for (int i = 0; i < 64; ++i)
        tile[i][t] = w[base + (size_t)i * DIM + t];   // coalesced
    __syncthreads();
    float v[DIM];
#pragma unroll
    for (int d = 0; d < DIM; ++d) v[d] = tile[t][d];  // stride 65 -> conflict-free
    wn2[blockIdx.x * 64 + t] = np_pairwise_sumsq64(v);
}

// R2 redesign: the R0/R1 structure (2 rows/thread = 128 persistent VGPRs) forced
// ~256 effective regs/wave (AGPR shuffling; VGPR_Count=128 was a forced cap) ->
// 2 waves/SIMD forever, VALU stream 1.7x inflated by spill moves. Here each
// thread owns ONE row (64 regs), codewords are wave-uniform loads (scalarizable
// to s_load -> SGPR operand of v_fma, zero LDS / zero VGPR staging in the hot
// loop). Grid 1024 blocks x 4 waves -> 4 blocks/CU -> 16 waves/CU even at the
// 128-VGPR worst case under __launch_bounds__(256,2).
__global__ __launch_bounds__(256, 2)
void vq_kernel(const float* __restrict__ x,
               const float* __restrict__ w,
               const float* __restrict__ wn2,
               float* __restrict__ out,
               float* __restrict__ partial) {
    __shared__ float cbd[NWAVES][64];
    __shared__ int   cbk[NWAVES][64];

    const int t = threadIdx.x;
    const int lane = t & 63;
    const int wv = t >> 6;                   // 4 waves, each owns a K-quarter
    const int rowbase = blockIdx.x * RPB;
    const int r = rowbase + lane;            // this thread's row

    // x row -> 64 VGPRs
    float xr[DIM];
    const float4* xv = (const float4*)(x + (size_t)r * DIM);
#pragma unroll
    for (int i = 0; i < 16; ++i) {
        float4 a = xv[i];
        xr[4 * i + 0] = a.x; xr[4 * i + 1] = a.y; xr[4 * i + 2] = a.z; xr[4 * i + 3] = a.w;
    }
    const float S = np_pairwise_sumsq64(xr);

    const int kbase = wv * KQ;               // this wave's K-quarter
    float best = 3.4e38f;
    int bi = kbase;

    for (int q = 0; q < KQ / 4; ++q) {       // quads of codewords, ascending k
        const int k = kbase + q * 4;
        const float* __restrict__ wk = w + (size_t)k * DIM;   // wave-uniform
        float a0 = 0.f, a1 = 0.f, a2 = 0.f, a3 = 0.f;
#pragma unroll
        for (int ph = 0; ph < 4; ++ph) {     // 16 dims per phase
            float u0[16], u1[16], u2[16], u3[16];
#pragma unroll
            for (int j = 0; j < 16; ++j) {
                u0[j] = wk[0 * DIM + ph * 16 + j];   // uniform -> s_load
                u1[j] = wk[1 * DIM + ph * 16 + j];
                u2[j] = wk[2 * DIM + ph * 16 + j];
                u3[j] = wk[3 * DIM + ph * 16 + j];
            }
#pragma unroll
            for (int j = 0; j < 16; ++j) {
                const float xd = xr[ph * 16 + j];
                // identical sequential-d FMA chain per (row, codeword) as R0/R1
                a0 = __builtin_fmaf(xd, u0[j], a0);
                a1 = __builtin_fmaf(xd, u1[j], a1);
                a2 = __builtin_fmaf(xd, u2[j], a2);
                a3 = __builtin_fmaf(xd, u3[j], a3);
            }
        }
        float wnA = wn2[k + 0], wnB = wn2[k + 1], wnC = wn2[k + 2], wnD = wn2[k + 3];
        float d0 = (S + wnA) - 2.0f * a0;
        float d1 = (S + wnB) - 2.0f * a1;
        float d2 = (S + wnC) - 2.0f * a2;
        float d3 = (S + wnD) - 2.0f * a3;
        if (d0 < best) { best = d0; bi = k + 0; }
        if (d1 < best) { best = d1; bi = k + 1; }
        if (d2 < best) { best = d2; bi = k + 2; }
        if (d3 < best) { best = d3; bi = k + 3; }
    }

    cbd[wv][lane] = best;  cbk[wv][lane] = bi;
    __syncthreads();

    if (wv == 0) {
        // cross-quarter argmin: ascending wave order, strict < -> lowest k wins
        float bd = cbd[0][lane]; int bk = cbk[0][lane];
#pragma unroll
        for (int qq = 1; qq < NWAVES; ++qq) {
            float dq = cbd[qq][lane]; int kq = cbk[qq][lane];
            if (dq < bd) { bd = dq; bk = kq; }
        }
        const int n = r;
        const int b = n >> 10;               // H*W = 1024
        const int hw = n & 1023;
        float* outq = out + 1 + (size_t)b * 65536 + hw;
        const float4* wr4 = (const float4*)(w + (size_t)bk * DIM);
        float lsum = 0.f;
#pragma unroll
        for (int i = 0; i < 16; ++i) {
            float4 u = wr4[i];
            float d0 = u.x - xr[4 * i + 0];
            float d1 = u.y - xr[4 * i + 1];
            float d2 = u.z - xr[4 * i + 2];
            float d3 = u.w - xr[4 * i + 3];
            lsum += d0 * d0; lsum += d1 * d1; lsum += d2 * d2; lsum += d3 * d3;
            outq[(size_t)(4 * i + 0) * 1024] = xr[4 * i + 0] + d0;
            outq[(size_t)(4 * i + 1) * 1024] = xr[4 * i + 1] + d1;
            outq[(size_t)(4 * i + 2) * 1024] = xr[4 * i + 2] + d2;
            outq[(size_t)(4 * i + 3) * 1024] = xr[4 * i + 3] + d3;
        }
        out[1 + Q_ELEMS + n] = (float)bk;
        // identical 64-lane shuffle tree over the same 64 rows as the old
        // per-wave subtree; partial[blk] = this block's 64-row sum (old A or B)
#pragma unroll
        for (int off = 32; off > 0; off >>= 1) lsum += __shfl_down(lsum, off, 64);
        if (lane == 0) partial[blockIdx.x] = lsum;
    }
}

__global__ void finish_kernel(const float* __restrict__ partial, float* __restrict__ out) {
    const int t = threadIdx.x;
    // Reconstruct the old tree bit-exactly: old P_t = fl(A_t + B_t) with
    // A_t = partial[2t], B_t = partial[2t+1]; old v = fl(P_t + P_{t+256}).
    float v = (partial[2 * t] + partial[2 * t + 1])
            + (partial[2 * (t + 256)] + partial[2 * (t + 256) + 1]);
#pragma unroll
    for (int off = 32; off > 0; off >>= 1) v += __shfl_down(v, off, 64);
    __shared__ float red[4];
    const int lane = t & 63;
    const int wv = t >> 6;
    if (lane == 0) red[wv] = v;
    __syncthreads();
    if (t == 0) {
        float total = (red[0] + red[1]) + (red[2] + red[3]);
        out[0] = total * (2.0f / (float)(N_ROWS * DIM));
    }
}

extern "C" void kernel_launch(void* const* d_in, const int* in_sizes, int n_in,
                              void* d_out, int out_size, void* d_ws, size_t ws_size,
                              hipStream_t stream) {
    const float* x = (const float*)d_in[0];
    const float* w = (const float*)d_in[1];
    float* out = (float*)d_out;

    char* ws = (char*)d_ws;
    float* wn2 = (float*)(ws + 0);
    float* partial = (float*)(ws + 4096);

    wnorm_kernel<<<KCB / 64, 64, 0, stream>>>(w, wn2);
    vq_kernel<<<N_ROWS / RPB, 256, 0, stream>>>(x, w, wn2, out, partial);
    finish_kernel<<<1, 256, 0, stream>>>(partial, out);
}

// Round 3
// 273.283 us; speedup vs baseline: 1.9979x; 1.9979x over previous
//
#include <hip/hip_runtime.h>

#define N_ROWS 65536
#define DIM 64
#define KCB 1024
#define Q_ELEMS 4194304   // 64*64*32*32
#define RPB 128           // rows per block (2 per lane, 64 lanes)
#define NWAVES 4          // waves per block; each owns a K-quarter
#define KQ 256            // codewords per wave

// ws layout (bytes): [0,4096) float wn2[1024]; [4096,6144) float partial[512]

// Bit-exact replica of numpy's pairwise sum of squares for 64 fp32 values.
__device__ __forceinline__ float np_pairwise_sumsq64(const float* v) {
#pragma clang fp contract(off)
    float r[8];
#pragma unroll
    for (int j = 0; j < 8; ++j) r[j] = v[j] * v[j];
#pragma unroll
    for (int i = 8; i < 64; i += 8) {
#pragma unroll
        for (int j = 0; j < 8; ++j) {
            float s = v[i + j] * v[i + j];
            r[j] = r[j] + s;
        }
    }
    return ((r[0] + r[1]) + (r[2] + r[3])) + ((r[4] + r[5]) + (r[6] + r[7]));
}

__global__ __launch_bounds__(64) void wnorm_kernel(const float* __restrict__ w,
                                                   float* __restrict__ wn2) {
    __shared__ float tile[64][65];
    const int t = threadIdx.x;
    const size_t base = (size_t)blockIdx.x * 64 * DIM;
#pragma unroll 4
    for (int i = 0; i < 64; ++i)
        tile[i][t] = w[base + (size_t)i * DIM + t];   // coalesced
    __syncthreads();
    float v[DIM];
#pragma unroll
    for (int d = 0; d < DIM; ++d) v[d] = tile[t][d];  // stride 65 -> conflict-free
    wn2[blockIdx.x * 64 + t] = np_pairwise_sumsq64(v);
}

// DPP rotate-by-1 within each 16-lane row (row_ror:1 = dpp_ctrl 0x121).
// Direction-proof: the codeword INDEX register rotates with the data, so
// whichever way the hardware rotates, (cw, wk, kid) stay consistent.
__device__ __forceinline__ float rot16f(float v) {
    return __int_as_float(__builtin_amdgcn_mov_dpp(__float_as_int(v), 0x121, 0xf, 0xf, false));
}
__device__ __forceinline__ int rot16i(int v) {
    return __builtin_amdgcn_mov_dpp(v, 0x121, 0xf, 0xf, false);
}

// R3 redesign: R0's broadcast-LDS dataflow is LDS-return-bus-bound
// (32768 b128/CU x ~12cyc ~= its 153us). Here the hot loop uses NO LDS:
// each lane's 2 x-rows stay in regs; one codeword (64 regs) + wn2 + index
// rotate through the lanes via DPP (row_ror:1) with __shfl_xor quadrant
// swaps every 16 steps. ~1.6 VALU instr per MAC -> ~90-110us ceiling.
// __launch_bounds__(256,1): allow the ~220-VGPR live set without spilling
// (2 waves/SIMD; grid 512x4 waves = 8 waves/CU = exact residency fit).
__global__ __launch_bounds__(256, 1)
void vq_kernel(const float* __restrict__ x,
               const float* __restrict__ w,
               const float* __restrict__ wn2,
               float* __restrict__ out,
               float* __restrict__ partial) {
    __shared__ float cbd[NWAVES][128];
    __shared__ int   cbk[NWAVES][128];
    __shared__ float red[NWAVES];

    const int t = threadIdx.x;
    const int lane = t & 63;
    const int wv = t >> 6;                   // 4 waves, each owns a K-quarter
    const int rowbase = blockIdx.x * RPB;
    const int r0 = rowbase + lane;           // this thread's two rows
    const int r1 = r0 + 64;

    // x rows -> 128 VGPRs (exact fp32, stationary)
    float xr0[DIM], xr1[DIM];
    const float4* xv0 = (const float4*)(x + (size_t)r0 * DIM);
    const float4* xv1 = (const float4*)(x + (size_t)r1 * DIM);
#pragma unroll
    for (int i = 0; i < 16; ++i) {
        float4 a = xv0[i];
        xr0[4 * i + 0] = a.x; xr0[4 * i + 1] = a.y; xr0[4 * i + 2] = a.z; xr0[4 * i + 3] = a.w;
        float4 b = xv1[i];
        xr1[4 * i + 0] = b.x; xr1[4 * i + 1] = b.y; xr1[4 * i + 2] = b.z; xr1[4 * i + 3] = b.w;
    }
    const float S0 = np_pairwise_sumsq64(xr0);
    const float S1 = np_pairwise_sumsq64(xr1);

    const int kbase = wv * KQ;               // this wave's K-quarter
    float best0 = 3.4e38f, best1 = 3.4e38f;
    int bi0 = kbase, bi1 = kbase;

#pragma unroll 1
    for (int g = 0; g < 4; ++g) {            // 4 groups of 64 codewords
        const int gbase = kbase + g * 64;
        // lane loads its codeword (64 regs) + wn2 + index
        float cw[DIM];
        const float4* wrow = (const float4*)(w + (size_t)(gbase + lane) * DIM);
#pragma unroll
        for (int i = 0; i < 16; ++i) {
            float4 u = wrow[i];
            cw[4 * i + 0] = u.x; cw[4 * i + 1] = u.y; cw[4 * i + 2] = u.z; cw[4 * i + 3] = u.w;
        }
        float wk = wn2[gbase + lane];
        int kid = gbase + lane;

#pragma unroll
        for (int sub = 0; sub < 4; ++sub) {
#pragma unroll 1
            for (int s = 0; s < 16; ++s) {
                // exact sequential-d dot chains (identical to R0's order):
                // first term as mul == fma into 0 (x*c rounds once either way)
                float a0 = xr0[0] * cw[0];
                float a1 = xr1[0] * cw[0];
#pragma unroll
                for (int d = 1; d < DIM; ++d) {
                    a0 = __builtin_fmaf(xr0[d], cw[d], a0);
                    a1 = __builtin_fmaf(xr1[d], cw[d], a1);
                }
                float dd0 = (S0 + wk) - 2.0f * a0;
                float dd1 = (S1 + wk) - 2.0f * a1;
                // first-min-by-k semantics under arbitrary visit order
                bool u0 = (dd0 < best0) || (dd0 == best0 && kid < bi0);
                if (u0) { best0 = dd0; bi0 = kid; }
                bool u1 = (dd1 < best1) || (dd1 == best1 && kid < bi1);
                if (u1) { best1 = dd1; bi1 = kid; }
                // rotate the codeword payload by 1 within 16-lane rows
#pragma unroll
                for (int d = 0; d < DIM; ++d) cw[d] = rot16f(cw[d]);
                wk = rot16f(wk);
                kid = rot16i(kid);
            }
            if (sub < 3) {                   // exchange quadrant sets
                const int m = (sub == 1) ? 32 : 16;
#pragma unroll
                for (int d = 0; d < DIM; ++d) cw[d] = __shfl_xor(cw[d], m, 64);
                wk = __shfl_xor(wk, m, 64);
                kid = __shfl_xor(kid, m, 64);
            }
        }
    }

    cbd[wv][lane]      = best0;  cbk[wv][lane]      = bi0;
    cbd[wv][64 + lane] = best1;  cbk[wv][64 + lane] = bi1;
    __syncthreads();

    float lsum = 0.f;
    if (t < 128) {
        const int rb = t;                                 // row-in-block
        // cross-quarter argmin: ascending wave order, strict < (quarters are
        // disjoint ascending k-ranges; within-quarter already first-min-by-k)
        float bd = cbd[0][rb]; int bk = cbk[0][rb];
#pragma unroll
        for (int q = 1; q < NWAVES; ++q) {
            float dq = cbd[q][rb]; int kq = cbk[q][rb];
            if (dq < bd) { bd = dq; bk = kq; }
        }
        float xcur[DIM];
        if (wv == 0) {
#pragma unroll
            for (int d = 0; d < DIM; ++d) xcur[d] = xr0[d];
        } else {
#pragma unroll
            for (int d = 0; d < DIM; ++d) xcur[d] = xr1[d];
        }
        const int n = rowbase + rb;
        const int b = n >> 10;               // H*W = 1024
        const int hw = n & 1023;
        float* outq = out + 1 + (size_t)b * 65536 + hw;
        const float4* wr4 = (const float4*)(w + (size_t)bk * DIM);
#pragma unroll
        for (int i = 0; i < 16; ++i) {
            float4 u = wr4[i];
            float d0 = u.x - xcur[4 * i + 0];
            float d1 = u.y - xcur[4 * i + 1];
            float d2 = u.z - xcur[4 * i + 2];
            float d3 = u.w - xcur[4 * i + 3];
            lsum += d0 * d0; lsum += d1 * d1; lsum += d2 * d2; lsum += d3 * d3;
            outq[(size_t)(4 * i + 0) * 1024] = xcur[4 * i + 0] + d0;
            outq[(size_t)(4 * i + 1) * 1024] = xcur[4 * i + 1] + d1;
            outq[(size_t)(4 * i + 2) * 1024] = xcur[4 * i + 2] + d2;
            outq[(size_t)(4 * i + 3) * 1024] = xcur[4 * i + 3] + d3;
        }
        out[1 + Q_ELEMS + n] = (float)bk;
    }
#pragma unroll
    for (int off = 32; off > 0; off >>= 1) lsum += __shfl_down(lsum, off, 64);
    if (lane == 0) red[wv] = lsum;
    __syncthreads();
    if (t == 0) partial[blockIdx.x] = (red[0] + red[1]) + (red[2] + red[3]);
}

__global__ void finish_kernel(const float* __restrict__ partial, float* __restrict__ out) {
    float v = partial[threadIdx.x] + partial[threadIdx.x + 256];
#pragma unroll
    for (int off = 32; off > 0; off >>= 1) v += __shfl_down(v, off, 64);
    __shared__ float red[4];
    const int lane = threadIdx.x & 63;
    const int wv = threadIdx.x >> 6;
    if (lane == 0) red[wv] = v;
    __syncthreads();
    if (threadIdx.x == 0) {
        float total = (red[0] + red[1]) + (red[2] + red[3]);
        out[0] = total * (2.0f / (float)(N_ROWS * DIM));
    }
}

extern "C" void kernel_launch(void* const* d_in, const int* in_sizes, int n_in,
                              void* d_out, int out_size, void* d_ws, size_t ws_size,
                              hipStream_t stream) {
    const float* x = (const float*)d_in[0];
    const float* w = (const float*)d_in[1];
    float* out = (float*)d_out;

    char* ws = (char*)d_ws;
    float* wn2 = (float*)(ws + 0);
    float* partial = (float*)(ws + 4096);

    wnorm_kernel<<<KCB / 64, 64, 0, stream>>>(w, wn2);
    vq_kernel<<<N_ROWS / RPB, 256, 0, stream>>>(x, w, wn2, out, partial);
    finish_kernel<<<1, 256, 0, stream>>>(partial, out);
}

// Round 6
// 236.384 us; speedup vs baseline: 2.3097x; 1.1561x over previous
//
#include <hip/hip_runtime.h>

#define N_ROWS 65536
#define DIM 64
#define KCB 1024
#define Q_ELEMS 4194304   // 64*64*32*32
#define RPB 64            // rows per block (1 row per lane)
#define NWAVES 4          // waves per block; each owns a K-quarter
#define KQ 256            // codewords per wave

// ws layout (bytes): [0,4096) float wn2[1024]; [4096,8192) float partial[1024]

typedef __attribute__((ext_vector_type(16))) float f32x16;
typedef __attribute__((ext_vector_type(2))) unsigned int u32x2;

// Bit-exact replica of numpy's pairwise sum of squares for 64 fp32 values.
__device__ __forceinline__ float np_pairwise_sumsq64(const float* v) {
#pragma clang fp contract(off)
    float r[8];
#pragma unroll
    for (int j = 0; j < 8; ++j) r[j] = v[j] * v[j];
#pragma unroll
    for (int i = 8; i < 64; i += 8) {
#pragma unroll
        for (int j = 0; j < 8; ++j) {
            float s = v[i + j] * v[i + j];
            r[j] = r[j] + s;
        }
    }
    return ((r[0] + r[1]) + (r[2] + r[3])) + ((r[4] + r[5]) + (r[6] + r[7]));
}

__global__ __launch_bounds__(64) void wnorm_kernel(const float* __restrict__ w,
                                                   float* __restrict__ wn2) {
    __shared__ float tile[64][65];
    const int t = threadIdx.x;
    const size_t base = (size_t)blockIdx.x * 64 * DIM;
#pragma unroll 4
    for (int i = 0; i < 64; ++i)
        tile[i][t] = w[base + (size_t)i * DIM + t];   // coalesced
    __syncthreads();
    float v[DIM];
#pragma unroll
    for (int d = 0; d < DIM; ++d) v[d] = tile[t][d];  // stride 65 -> conflict-free
    wn2[blockIdx.x * 64 + t] = np_pairwise_sumsq64(v);
}

// Force a wave-uniform 64-bit address into an SGPR pair the "s" constraint can
// bind (wv=threadIdx>>6 is divergent to uniformity analysis even though it is
// wave-uniform in fact; readfirstlane makes it explicit — HK idiom).
__device__ __forceinline__ u32x2 sgpr_addr(const void* p) {
    unsigned long long a = (unsigned long long)p;
    u32x2 r;
    r.x = (unsigned)__builtin_amdgcn_readfirstlane((int)(unsigned)a);
    r.y = (unsigned)__builtin_amdgcn_readfirstlane((int)(unsigned)(a >> 32));
    return r;
}

// R6 (= R5 + early-clobber): codeword broadcast via the SCALAR pipe.
// Delivery paths eliminated: LDS broadcast = return-bus-bound (R0, 153us
// wall); VMEM uniform loads serialize (R2, 497us); DPP register rotation
// blows the VGPR budget (R3, 224us spill-inflated). s_load_dwordx16 moves
// 64B of wave-uniform codeword per instruction into SGPRs on the scalar
// pipe; v_fma_f32 folds one SGPR operand -> broadcast costs the VALU nothing.
// R5 crashed at runtime: plain "=s" outputs may overlap the input base pairs
// (allocator assumes inputs die before outputs are written — false for async
// SMEM returns) -> base corrupted -> wild address fault. "=&s" early-clobber
// forces disjoint allocation (65 out + 4 in + ~20 state < 102 SGPRs).
// lgkmcnt(0) stays INSIDE the asm block; consumers read the asm outputs, so
// dataflow ordering prevents any hoisting past the wait.
// Geometry: 1 row/lane (64 VGPRs x), 4 waves/block each owning an ascending
// K-quarter, grid 1024 = 4 blocks/CU = 4 waves/SIMD (launch_bounds(256,4)).
// Per cw ~145 VALU cyc; 300cy SMEM latency hidden by 3 sibling waves.
// Floor ~4*256*145cy ~= 62us/SIMD.
__global__ __launch_bounds__(256, 4)
void vq_kernel(const float* __restrict__ x,
               const float* __restrict__ w,
               const float* __restrict__ wn2,
               float* __restrict__ out,
               float* __restrict__ partial) {
    __shared__ float cbd[NWAVES][64];
    __shared__ int   cbk[NWAVES][64];

    const int t = threadIdx.x;
    const int lane = t & 63;
    const int wv = t >> 6;                   // 4 waves, each owns a K-quarter
    const int rowbase = blockIdx.x * RPB;
    const int r = rowbase + lane;            // this thread's row

    // x row -> 64 VGPRs (exact fp32, stationary)
    float xr[DIM];
    const float4* xv = (const float4*)(x + (size_t)r * DIM);
#pragma unroll
    for (int i = 0; i < 16; ++i) {
        float4 a = xv[i];
        xr[4 * i + 0] = a.x; xr[4 * i + 1] = a.y; xr[4 * i + 2] = a.z; xr[4 * i + 3] = a.w;
    }
    const float S = np_pairwise_sumsq64(xr);

    const int kbase = wv * KQ;               // this wave's K-quarter
    float best = 3.4e38f;
    int bi = kbase;

#pragma unroll 1
    for (int q = 0; q < KQ; ++q) {           // ascending k within the quarter
        const int k = kbase + q;
        const u32x2 wb = sgpr_addr(w + (size_t)k * DIM);
        const u32x2 nb = sgpr_addr(wn2 + k);
        f32x16 u0, u1, u2, u3;
        float wkn;
        asm volatile(
            "s_load_dwordx16 %0, %5, 0x0\n\t"
            "s_load_dwordx16 %1, %5, 0x40\n\t"
            "s_load_dwordx16 %2, %5, 0x80\n\t"
            "s_load_dwordx16 %3, %5, 0xc0\n\t"
            "s_load_dword %4, %6, 0x0\n\t"
            "s_waitcnt lgkmcnt(0)"
            : "=&s"(u0), "=&s"(u1), "=&s"(u2), "=&s"(u3), "=&s"(wkn)
            : "s"(wb), "s"(nb));

        // exact sequential-d FMA chain, identical to R0/R2 (init 0, d=0..63)
        float a = 0.f;
#pragma unroll
        for (int j = 0; j < 16; ++j) a = __builtin_fmaf(xr[j],      u0[j], a);
#pragma unroll
        for (int j = 0; j < 16; ++j) a = __builtin_fmaf(xr[16 + j], u1[j], a);
#pragma unroll
        for (int j = 0; j < 16; ++j) a = __builtin_fmaf(xr[32 + j], u2[j], a);
#pragma unroll
        for (int j = 0; j < 16; ++j) a = __builtin_fmaf(xr[48 + j], u3[j], a);

        float dd = (S + wkn) - 2.0f * a;
        if (dd < best) { best = dd; bi = k; }        // strict < : first-min, k ascending
    }

    cbd[wv][lane] = best;  cbk[wv][lane] = bi;
    __syncthreads();

    if (wv == 0) {
        // cross-quarter argmin: ascending wave order, strict < -> lowest k wins
        float bd = cbd[0][lane]; int bk = cbk[0][lane];
#pragma unroll
        for (int qq = 1; qq < NWAVES; ++qq) {
            float dq = cbd[qq][lane]; int kq = cbk[qq][lane];
            if (dq < bd) { bd = dq; bk = kq; }
        }
        const int n = r;
        const int b = n >> 10;               // H*W = 1024
        const int hw = n & 1023;
        float* outq = out + 1 + (size_t)b * 65536 + hw;
        const float4* wr4 = (const float4*)(w + (size_t)bk * DIM);
        float lsum = 0.f;
#pragma unroll
        for (int i = 0; i < 16; ++i) {
            float4 u = wr4[i];
            float d0 = u.x - xr[4 * i + 0];
            float d1 = u.y - xr[4 * i + 1];
            float d2 = u.z - xr[4 * i + 2];
            float d3 = u.w - xr[4 * i + 3];
            lsum += d0 * d0; lsum += d1 * d1; lsum += d2 * d2; lsum += d3 * d3;
            outq[(size_t)(4 * i + 0) * 1024] = xr[4 * i + 0] + d0;
            outq[(size_t)(4 * i + 1) * 1024] = xr[4 * i + 1] + d1;
            outq[(size_t)(4 * i + 2) * 1024] = xr[4 * i + 2] + d2;
            outq[(size_t)(4 * i + 3) * 1024] = xr[4 * i + 3] + d3;
        }
        out[1 + Q_ELEMS + n] = (float)bk;
        // 64-lane shuffle tree over this block's 64 rows (same subtree as the
        // original per-wave tree); partial[blk] = old A or B half-block sum
#pragma unroll
        for (int off = 32; off > 0; off >>= 1) lsum += __shfl_down(lsum, off, 64);
        if (lane == 0) partial[blockIdx.x] = lsum;
    }
}

__global__ void finish_kernel(const float* __restrict__ partial, float* __restrict__ out) {
    const int t = threadIdx.x;
    // Reconstruct the original tree bit-exactly: old P_t = fl(A_t + B_t) with
    // A_t = partial[2t], B_t = partial[2t+1]; old v = fl(P_t + P_{t+256}).
    float v = (partial[2 * t] + partial[2 * t + 1])
            + (partial[2 * (t + 256)] + partial[2 * (t + 256) + 1]);
#pragma unroll
    for (int off = 32; off > 0; off >>= 1) v += __shfl_down(v, off, 64);
    __shared__ float red[4];
    const int lane = t & 63;
    const int wv = t >> 6;
    if (lane == 0) red[wv] = v;
    __syncthreads();
    if (t == 0) {
        float total = (red[0] + red[1]) + (red[2] + red[3]);
        out[0] = total * (2.0f / (float)(N_ROWS * DIM));
    }
}

extern "C" void kernel_launch(void* const* d_in, const int* in_sizes, int n_in,
                              void* d_out, int out_size, void* d_ws, size_t ws_size,
                              hipStream_t stream) {
    const float* x = (const float*)d_in[0];
    const float* w = (const float*)d_in[1];
    float* out = (float*)d_out;

    char* ws = (char*)d_ws;
    float* wn2 = (float*)(ws + 0);
    float* partial = (float*)(ws + 4096);

    wnorm_kernel<<<KCB / 64, 64, 0, stream>>>(w, wn2);
    vq_kernel<<<N_ROWS / RPB, 256, 0, stream>>>(x, w, wn2, out, partial);
    finish_kernel<<<1, 256, 0, stream>>>(partial, out);
}

// Round 7
// 230.472 us; speedup vs baseline: 2.3690x; 1.0257x over previous
//
#include <hip/hip_runtime.h>

#define N_ROWS 65536
#define DIM 64
#define KCB 1024
#define Q_ELEMS 4194304   // 64*64*32*32
#define RPB 64            // rows per block (1 row per lane)
#define NWAVES 4          // waves per block; each owns a K-quarter
#define KQ 256            // codewords per wave

// ws layout (bytes): [0,4096) float wn2[1024]; [4096,8192) float partial[1024]

typedef __attribute__((ext_vector_type(16))) float f32x16;

// Bit-exact replica of numpy's pairwise sum of squares for 64 fp32 values.
__device__ __forceinline__ float np_pairwise_sumsq64(const float* v) {
#pragma clang fp contract(off)
    float r[8];
#pragma unroll
    for (int j = 0; j < 8; ++j) r[j] = v[j] * v[j];
#pragma unroll
    for (int i = 8; i < 64; i += 8) {
#pragma unroll
        for (int j = 0; j < 8; ++j) {
            float s = v[i + j] * v[i + j];
            r[j] = r[j] + s;
        }
    }
    return ((r[0] + r[1]) + (r[2] + r[3])) + ((r[4] + r[5]) + (r[6] + r[7]));
}

__global__ __launch_bounds__(64) void wnorm_kernel(const float* __restrict__ w,
                                                   float* __restrict__ wn2) {
    __shared__ float tile[64][65];
    const int t = threadIdx.x;
    const size_t base = (size_t)blockIdx.x * 64 * DIM;
#pragma unroll 4
    for (int i = 0; i < 64; ++i)
        tile[i][t] = w[base + (size_t)i * DIM + t];   // coalesced
    __syncthreads();
    float v[DIM];
#pragma unroll
    for (int d = 0; d < DIM; ++d) v[d] = tile[t][d];  // stride 65 -> conflict-free
    wn2[blockIdx.x * 64 + t] = np_pairwise_sumsq64(v);
}

// Make a wave-uniform 64-bit address explicit-uniform (SGPR-resident) once.
// Derived arithmetic on the result (+=256 etc.) stays uniform -> SALU adds,
// and the "s" asm constraint binds an SGPR pair legally (unlike R4, where a
// divergent-looking value silently bound a VGPR and the assembler rejected it).
__device__ __forceinline__ unsigned long long uniform_addr(const void* p) {
    unsigned long long a = (unsigned long long)p;
    unsigned lo = (unsigned)__builtin_amdgcn_readfirstlane((int)(unsigned)a);
    unsigned hi = (unsigned)__builtin_amdgcn_readfirstlane((int)(unsigned)(a >> 32));
    return ((unsigned long long)hi << 32) | lo;
}

// R7 (= R6 with the VGPR budget fixed): R6's __launch_bounds__(256,4) budgeted
// ~64 VGPRs (VGPR_Count=48!) while the live set (xr[64]+acc+misc ~90) needs
// more -> part of xr lived in AGPRs and EVERY FMA paid a v_accvgpr_read ->
// VALU stream doubled (measured busy 134us vs 59us lean hand-count).
// (256,2) budgets 128 VGPRs; usage ~90 still gets 4 waves/SIMD from HW
// (<=128-VGPR occupancy step), so occupancy is unchanged and the AGPR tax
// disappears. Also: addressing hoisted out of the loop (readfirstlane once,
// scalar base += 256/4 per iter on SALU) -> ~10 fewer VALU/cw.
// Delivery ledger: LDS broadcast = return-bus wall (R0, 153us); VMEM uniform
// loads serialize (R2, 497us); DPP rotation = VGPR wall (R3, 224us);
// SMEM s_load_dwordx16 = scalar-pipe broadcast, free at the VALU (R6, works).
// Floor: 4 waves x 256 cw x ~140cyc ~= 60us/SIMD.
__global__ __launch_bounds__(256, 2)
void vq_kernel(const float* __restrict__ x,
               const float* __restrict__ w,
               const float* __restrict__ wn2,
               float* __restrict__ out,
               float* __restrict__ partial) {
    __shared__ float cbd[NWAVES][64];
    __shared__ int   cbk[NWAVES][64];

    const int t = threadIdx.x;
    const int lane = t & 63;
    const int wv = t >> 6;                   // 4 waves, each owns a K-quarter
    const int rowbase = blockIdx.x * RPB;
    const int r = rowbase + lane;            // this thread's row

    // x row -> 64 VGPRs (exact fp32, stationary)
    float xr[DIM];
    const float4* xv = (const float4*)(x + (size_t)r * DIM);
#pragma unroll
    for (int i = 0; i < 16; ++i) {
        float4 a = xv[i];
        xr[4 * i + 0] = a.x; xr[4 * i + 1] = a.y; xr[4 * i + 2] = a.z; xr[4 * i + 3] = a.w;
    }
    const float S = np_pairwise_sumsq64(xr);

    const int kbase = wv * KQ;               // this wave's K-quarter
    float best = 3.4e38f;
    int bi = kbase;

    // wave-uniform base addresses, hoisted; advanced on the SALU per iteration
    unsigned long long wb = uniform_addr(w + (size_t)kbase * DIM);
    unsigned long long nb = uniform_addr(wn2 + kbase);

#pragma unroll 1
    for (int q = 0; q < KQ; ++q) {           // ascending k within the quarter
        const int k = kbase + q;
        f32x16 u0, u1, u2, u3;
        float wkn;
        asm volatile(
            "s_load_dwordx16 %0, %5, 0x0\n\t"
            "s_load_dwordx16 %1, %5, 0x40\n\t"
            "s_load_dwordx16 %2, %5, 0x80\n\t"
            "s_load_dwordx16 %3, %5, 0xc0\n\t"
            "s_load_dword %4, %6, 0x0\n\t"
            "s_waitcnt lgkmcnt(0)"
            : "=&s"(u0), "=&s"(u1), "=&s"(u2), "=&s"(u3), "=&s"(wkn)
            : "s"(wb), "s"(nb));
        wb += 256;                           // uniform -> s_add_u32/s_addc_u32
        nb += 4;

        // exact sequential-d FMA chain, identical to R0/R2 (init 0, d=0..63)
        float a = 0.f;
#pragma unroll
        for (int j = 0; j < 16; ++j) a = __builtin_fmaf(xr[j],      u0[j], a);
#pragma unroll
        for (int j = 0; j < 16; ++j) a = __builtin_fmaf(xr[16 + j], u1[j], a);
#pragma unroll
        for (int j = 0; j < 16; ++j) a = __builtin_fmaf(xr[32 + j], u2[j], a);
#pragma unroll
        for (int j = 0; j < 16; ++j) a = __builtin_fmaf(xr[48 + j], u3[j], a);

        float dd = (S + wkn) - 2.0f * a;
        if (dd < best) { best = dd; bi = k; }        // strict < : first-min, k ascending
    }

    cbd[wv][lane] = best;  cbk[wv][lane] = bi;
    __syncthreads();

    if (wv == 0) {
        // cross-quarter argmin: ascending wave order, strict < -> lowest k wins
        float bd = cbd[0][lane]; int bk = cbk[0][lane];
#pragma unroll
        for (int qq = 1; qq < NWAVES; ++qq) {
            float dq = cbd[qq][lane]; int kq = cbk[qq][lane];
            if (dq < bd) { bd = dq; bk = kq; }
        }
        const int n = r;
        const int b = n >> 10;               // H*W = 1024
        const int hw = n & 1023;
        float* outq = out + 1 + (size_t)b * 65536 + hw;
        const float4* wr4 = (const float4*)(w + (size_t)bk * DIM);
        float lsum = 0.f;
#pragma unroll
        for (int i = 0; i < 16; ++i) {
            float4 u = wr4[i];
            float d0 = u.x - xr[4 * i + 0];
            float d1 = u.y - xr[4 * i + 1];
            float d2 = u.z - xr[4 * i + 2];
            float d3 = u.w - xr[4 * i + 3];
            lsum += d0 * d0; lsum += d1 * d1; lsum += d2 * d2; lsum += d3 * d3;
            outq[(size_t)(4 * i + 0) * 1024] = xr[4 * i + 0] + d0;
            outq[(size_t)(4 * i + 1) * 1024] = xr[4 * i + 1] + d1;
            outq[(size_t)(4 * i + 2) * 1024] = xr[4 * i + 2] + d2;
            outq[(size_t)(4 * i + 3) * 1024] = xr[4 * i + 3] + d3;
        }
        out[1 + Q_ELEMS + n] = (float)bk;
        // 64-lane shuffle tree over this block's 64 rows (same subtree as the
        // original per-wave tree); partial[blk] = old A or B half-block sum
#pragma unroll
        for (int off = 32; off > 0; off >>= 1) lsum += __shfl_down(lsum, off, 64);
        if (lane == 0) partial[blockIdx.x] = lsum;
    }
}

__global__ void finish_kernel(const float* __restrict__ partial, float* __restrict__ out) {
    const int t = threadIdx.x;
    // Reconstruct the original tree bit-exactly: old P_t = fl(A_t + B_t) with
    // A_t = partial[2t], B_t = partial[2t+1]; old v = fl(P_t + P_{t+256}).
    float v = (partial[2 * t] + partial[2 * t + 1])
            + (partial[2 * (t + 256)] + partial[2 * (t + 256) + 1]);
#pragma unroll
    for (int off = 32; off > 0; off >>= 1) v += __shfl_down(v, off, 64);
    __shared__ float red[4];
    const int lane = t & 63;
    const int wv = t >> 6;
    if (lane == 0) red[wv] = v;
    __syncthreads();
    if (t == 0) {
        float total = (red[0] + red[1]) + (red[2] + red[3]);
        out[0] = total * (2.0f / (float)(N_ROWS * DIM));
    }
}

extern "C" void kernel_launch(void* const* d_in, const int* in_sizes, int n_in,
                              void* d_out, int out_size, void* d_ws, size_t ws_size,
                              hipStream_t stream) {
    const float* x = (const float*)d_in[0];
    const float* w = (const float*)d_in[1];
    float* out = (float*)d_out;

    char* ws = (char*)d_ws;
    float* wn2 = (float*)(ws + 0);
    float* partial = (float*)(ws + 4096);

    wnorm_kernel<<<KCB / 64, 64, 0, stream>>>(w, wn2);
    vq_kernel<<<N_ROWS / RPB, 256, 0, stream>>>(x, w, wn2, out, partial);
    finish_kernel<<<1, 256, 0, stream>>>(partial, out);
}